// Round 6
// baseline (332.613 us; speedup 1.0000x reference)
//
#include <hip/hip_runtime.h>
#include <math.h>

// Problem constants (from reference): B=128, N=131072, D=1
#define PF_B 128
#define PF_N 131072
#define TPB 256                 // threads per block
#define EPT 8                   // elements per thread (2 x float4)
#define EPB (TPB * EPT)         // 2048 elements per block
#define BLOCKS_PER_BATCH (PF_N / EPB)   // 64  (== wave size, used by pf_final)

typedef float v4f __attribute__((ext_vector_type(4)));

// d_out layout: [new_particles: B*N floats][w: B*N floats]
// d_ws  layout: [partials: B * BLOCKS_PER_BATCH floats = 8192 floats = 32 KB]

__device__ __forceinline__ void compute_elem(
    float x, float n, float wt, float c, float ob,
    float& xnew, float& wv)
{
    // mean = x/2 + 25*x/(x^2+1) + 8*cos(1.2*t); xnew = mean + noise*sqrt(10)
    const float mean = x * 0.5f + 25.0f * (x / (x * x + 1.0f)) + c;
    xnew = mean + n * 3.16227770f;                 // np.float32(sqrt(10))
    const float om = (xnew * xnew) / 20.0f;
    const float d  = ob - om;
    const float lp = -0.5f * d * d + (-0.9189385f); // -0.5*log(2*pi)
    wv = wt * __expf(lp);
}

// Pass 1: compute per-block weight sums only. Normal (allocating) loads so the
// 201 MB of inputs become L3-resident for pass 2. Writes just 1 float/block.
__global__ __launch_bounds__(TPB) void pf_sum(
    const float* __restrict__ particles,
    const float* __restrict__ weights,
    const float* __restrict__ obs,        // [B]
    const float* __restrict__ noise,
    const int*   __restrict__ tstep,      // [1]
    float* __restrict__ partials)         // [B * BLOCKS_PER_BATCH]
{
    const int b     = blockIdx.x / BLOCKS_PER_BATCH;
    const int chunk = blockIdx.x % BLOCKS_PER_BATCH;
    const long base = (long)b * PF_N + (long)chunk * EPB;

    const float ob = obs[b];
    const float c  = 8.0f * cosf(1.2f * (float)(*tstep));

    float lsum = 0.0f;

    #pragma unroll
    for (int k = 0; k < EPT / 4; ++k) {
        const long idx = base + (long)k * (TPB * 4) + (long)threadIdx.x * 4;
        const v4f x4  = *(const v4f*)(particles + idx);
        const v4f n4  = *(const v4f*)(noise + idx);
        const v4f wt4 = *(const v4f*)(weights + idx);
        #pragma unroll
        for (int j = 0; j < 4; ++j) {
            float xn, wv;
            compute_elem(x4[j], n4[j], wt4[j], c, ob, xn, wv);
            lsum += wv;        // wv depends on xn -> full chain stays live
        }
    }

    // 64-lane wave reduction, cross-wave via LDS, one store per block
    #pragma unroll
    for (int off = 32; off > 0; off >>= 1)
        lsum += __shfl_down(lsum, off, 64);

    __shared__ float red[TPB / 64];
    if ((threadIdx.x & 63) == 0) red[threadIdx.x >> 6] = lsum;
    __syncthreads();
    if (threadIdx.x == 0) {
        float s = 0.0f;
        #pragma unroll
        for (int i = 0; i < TPB / 64; ++i) s += red[i];
        partials[blockIdx.x] = s;   // no memset, no atomics needed
    }
}

// Pass 2: re-read inputs (L3-hit), recompute, write np and normalized w
// with non-temporal stores (never re-read; keeps L3 clean for inputs).
__global__ __launch_bounds__(TPB) void pf_final(
    const float* __restrict__ particles,
    const float* __restrict__ weights,
    const float* __restrict__ obs,        // [B]
    const float* __restrict__ noise,
    const int*   __restrict__ tstep,      // [1]
    const float* __restrict__ partials,   // [B * BLOCKS_PER_BATCH]
    float* __restrict__ np_out,           // [B*N]
    float* __restrict__ w_out)            // [B*N], normalized on write
{
    const int b     = blockIdx.x / BLOCKS_PER_BATCH;
    const int chunk = blockIdx.x % BLOCKS_PER_BATCH;
    const long base = (long)b * PF_N + (long)chunk * EPB;

    const float ob = obs[b];
    const float c  = 8.0f * cosf(1.2f * (float)(*tstep));

    // Batch sum: 64 partials per batch == one per lane; butterfly-reduce so
    // every lane ends with the total. Each wave does this redundantly (cheap,
    // L2-hit, no LDS/sync).
    const int lane = threadIdx.x & 63;
    float p = partials[b * BLOCKS_PER_BATCH + lane];
    #pragma unroll
    for (int off = 32; off > 0; off >>= 1)
        p += __shfl_xor(p, off, 64);
    const float inv = 1.0f / p;

    #pragma unroll
    for (int k = 0; k < EPT / 4; ++k) {
        const long idx = base + (long)k * (TPB * 4) + (long)threadIdx.x * 4;
        const v4f x4  = *(const v4f*)(particles + idx);   // L3-hit (pass 1 populated)
        const v4f n4  = *(const v4f*)(noise + idx);
        const v4f wt4 = *(const v4f*)(weights + idx);

        v4f xn, wn;
        #pragma unroll
        for (int j = 0; j < 4; ++j) {
            float xnew, wv;
            compute_elem(x4[j], n4[j], wt4[j], c, ob, xnew, wv);
            xn[j] = xnew;
            wn[j] = wv * inv;     // normalized at the single write
        }

        // Outputs are never re-read: bypass cache so L3 keeps holding inputs.
        __builtin_nontemporal_store(xn, (v4f*)(np_out + idx));
        __builtin_nontemporal_store(wn, (v4f*)(w_out + idx));
    }
}

extern "C" void kernel_launch(void* const* d_in, const int* in_sizes, int n_in,
                              void* d_out, int out_size, void* d_ws, size_t ws_size,
                              hipStream_t stream) {
    const float* particles = (const float*)d_in[0];
    const float* weights   = (const float*)d_in[1];
    const float* obs       = (const float*)d_in[2];
    const float* noise     = (const float*)d_in[3];
    // d_in[4] = uniforms: dead code in the reference (resample output unused)
    const int*   tstep     = (const int*)d_in[5];

    float* np_out   = (float*)d_out;                     // new_particles [B*N]
    float* w_out    = (float*)d_out + (long)PF_B * PF_N; // weights      [B*N]
    float* partials = (float*)d_ws;                      // [B*64] = 32 KB

    const int grid = PF_B * BLOCKS_PER_BATCH;  // 8192 blocks
    pf_sum<<<grid, TPB, 0, stream>>>(particles, weights, obs, noise, tstep,
                                     partials);
    pf_final<<<grid, TPB, 0, stream>>>(particles, weights, obs, noise, tstep,
                                       partials, np_out, w_out);
}

// Round 10
// 332.116 us; speedup vs baseline: 1.0015x; 1.0015x over previous
//
#include <hip/hip_runtime.h>
#include <math.h>

// Problem constants (from reference): B=128, N=131072, D=1
#define PF_B 128
#define PF_N 131072
#define TPB 256                 // threads per block
#define VPT 4                   // float4 loads per stream per thread
#define EPT (VPT * 4)           // 16 elements per thread
#define EPB (TPB * EPT)         // 4096 elements per block
#define BLOCKS_PER_BATCH (PF_N / EPB)   // 32

typedef float v4f __attribute__((ext_vector_type(4)));

// d_out layout: [new_particles: B*N floats][w: B*N floats]
// d_ws  layout: [partials: B * BLOCKS_PER_BATCH floats = 4096 floats]

__device__ __forceinline__ void compute_elem(
    float x, float n, float wt, float c, float ob,
    float& xnew, float& wv)
{
    // mean = x/2 + 25*x/(x^2+1) + 8*cos(1.2*t); xnew = mean + noise*sqrt(10)
    const float mean = x * 0.5f + 25.0f * (x / (x * x + 1.0f)) + c;
    xnew = mean + n * 3.16227770f;                 // np.float32(sqrt(10))
    const float om = (xnew * xnew) / 20.0f;
    const float d  = ob - om;
    const float lp = -0.5f * d * d + (-0.9189385f); // -0.5*log(2*pi)
    wv = wt * __expf(lp);
}

// Pass 1: per-block weight sums. MLP fix: issue all 12 independent
// global_load_dwordx4 (4 per stream x 3 streams = 192 B/lane in flight)
// before consuming any -- round-6 counters showed VGPR=20 allowed only ~3
// loads in flight -> 2.5 TB/s latency-bound read.
__global__ __launch_bounds__(TPB) void pf_sum(
    const float* __restrict__ particles,
    const float* __restrict__ weights,
    const float* __restrict__ obs,        // [B]
    const float* __restrict__ noise,
    const int*   __restrict__ tstep,      // [1]
    float* __restrict__ partials)         // [B * BLOCKS_PER_BATCH]
{
    const int b     = blockIdx.x / BLOCKS_PER_BATCH;
    const int chunk = blockIdx.x % BLOCKS_PER_BATCH;
    const long base = (long)b * PF_N + (long)chunk * EPB
                    + (long)threadIdx.x * 4;

    const float ob = obs[b];
    const float c  = 8.0f * cosf(1.2f * (float)(*tstep));

    // All loads issued before any use; static indexing keeps these in VGPRs.
    v4f x4[VPT], n4[VPT], wt4[VPT];
    #pragma unroll
    for (int k = 0; k < VPT; ++k)
        x4[k]  = *(const v4f*)(particles + base + (long)k * (TPB * 4));
    #pragma unroll
    for (int k = 0; k < VPT; ++k)
        n4[k]  = *(const v4f*)(noise + base + (long)k * (TPB * 4));
    #pragma unroll
    for (int k = 0; k < VPT; ++k)
        wt4[k] = *(const v4f*)(weights + base + (long)k * (TPB * 4));

    float lsum = 0.0f;
    #pragma unroll
    for (int k = 0; k < VPT; ++k) {
        #pragma unroll
        for (int j = 0; j < 4; ++j) {
            float xn, wv;
            compute_elem(x4[k][j], n4[k][j], wt4[k][j], c, ob, xn, wv);
            lsum += wv;
        }
    }

    // 64-lane wave reduction, cross-wave via LDS, one store per block
    #pragma unroll
    for (int off = 32; off > 0; off >>= 1)
        lsum += __shfl_down(lsum, off, 64);

    __shared__ float red[TPB / 64];
    if ((threadIdx.x & 63) == 0) red[threadIdx.x >> 6] = lsum;
    __syncthreads();
    if (threadIdx.x == 0) {
        float s = 0.0f;
        #pragma unroll
        for (int i = 0; i < TPB / 64; ++i) s += red[i];
        partials[blockIdx.x] = s;   // no memset, no atomics needed
    }
}

// Pass 2: re-read inputs (L3-warm from pass 1), recompute, write np and
// normalized w with non-temporal stores (outputs never re-read).
__global__ __launch_bounds__(TPB) void pf_final(
    const float* __restrict__ particles,
    const float* __restrict__ weights,
    const float* __restrict__ obs,        // [B]
    const float* __restrict__ noise,
    const int*   __restrict__ tstep,      // [1]
    const float* __restrict__ partials,   // [B * BLOCKS_PER_BATCH]
    float* __restrict__ np_out,           // [B*N]
    float* __restrict__ w_out)            // [B*N], normalized on write
{
    const int b     = blockIdx.x / BLOCKS_PER_BATCH;
    const int chunk = blockIdx.x % BLOCKS_PER_BATCH;
    const long base = (long)b * PF_N + (long)chunk * EPB
                    + (long)threadIdx.x * 4;

    const float ob = obs[b];
    const float c  = 8.0f * cosf(1.2f * (float)(*tstep));

    // Batch sum: 32 partials per batch; lanes 0-31 and 32-63 each hold the
    // set (lane&31), butterfly over 32 gives every lane the total.
    const int lane = threadIdx.x & 63;
    float p = partials[b * BLOCKS_PER_BATCH + (lane & (BLOCKS_PER_BATCH - 1))];
    #pragma unroll
    for (int off = BLOCKS_PER_BATCH / 2; off > 0; off >>= 1)
        p += __shfl_xor(p, off, 64);
    const float inv = 1.0f / p;

    // Same MLP structure: all 12 loads in flight before first use.
    v4f x4[VPT], n4[VPT], wt4[VPT];
    #pragma unroll
    for (int k = 0; k < VPT; ++k)
        x4[k]  = *(const v4f*)(particles + base + (long)k * (TPB * 4));
    #pragma unroll
    for (int k = 0; k < VPT; ++k)
        n4[k]  = *(const v4f*)(noise + base + (long)k * (TPB * 4));
    #pragma unroll
    for (int k = 0; k < VPT; ++k)
        wt4[k] = *(const v4f*)(weights + base + (long)k * (TPB * 4));

    #pragma unroll
    for (int k = 0; k < VPT; ++k) {
        v4f xn, wn;
        #pragma unroll
        for (int j = 0; j < 4; ++j) {
            float xnew, wv;
            compute_elem(x4[k][j], n4[k][j], wt4[k][j], c, ob, xnew, wv);
            xn[j] = xnew;
            wn[j] = wv * inv;     // normalized at the single write
        }
        __builtin_nontemporal_store(xn, (v4f*)(np_out + base + (long)k * (TPB * 4)));
        __builtin_nontemporal_store(wn, (v4f*)(w_out  + base + (long)k * (TPB * 4)));
    }
}

extern "C" void kernel_launch(void* const* d_in, const int* in_sizes, int n_in,
                              void* d_out, int out_size, void* d_ws, size_t ws_size,
                              hipStream_t stream) {
    const float* particles = (const float*)d_in[0];
    const float* weights   = (const float*)d_in[1];
    const float* obs       = (const float*)d_in[2];
    const float* noise     = (const float*)d_in[3];
    // d_in[4] = uniforms: dead code in the reference (resample output unused)
    const int*   tstep     = (const int*)d_in[5];

    float* np_out   = (float*)d_out;                     // new_particles [B*N]
    float* w_out    = (float*)d_out + (long)PF_B * PF_N; // weights      [B*N]
    float* partials = (float*)d_ws;                      // [B*32]

    const int grid = PF_B * BLOCKS_PER_BATCH;  // 4096 blocks
    pf_sum<<<grid, TPB, 0, stream>>>(particles, weights, obs, noise, tstep,
                                     partials);
    pf_final<<<grid, TPB, 0, stream>>>(particles, weights, obs, noise, tstep,
                                       partials, np_out, w_out);
}

// Round 13
// 331.399 us; speedup vs baseline: 1.0037x; 1.0022x over previous
//
#include <hip/hip_runtime.h>
#include <math.h>

// Problem constants (from reference): B=128, N=131072, D=1
#define PF_B 128
#define PF_N 131072
#define TPB 256                 // threads per block
#define VPT 4                   // float4 loads per stream per thread (pass 1)
#define EPT (VPT * 4)           // 16 elements per thread
#define EPB (TPB * EPT)         // 4096 elements per block
#define BLOCKS_PER_BATCH (PF_N / EPB)   // 32 (pass 1)

// Pass 2 geometry: pure scale-copy of w
#define NORM_BPB 16                          // blocks per batch
#define NORM_EPB (PF_N / NORM_BPB)           // 8192 elems per block
#define NORM_VPT (NORM_EPB / (TPB * 4))      // 8 float4 per thread

typedef float v4f __attribute__((ext_vector_type(4)));

// d_out layout: [new_particles: B*N floats][w: B*N floats]
// d_ws  layout: [partials: B * BLOCKS_PER_BATCH floats = 4096 floats]

__device__ __forceinline__ void compute_elem(
    float x, float n, float wt, float c, float ob,
    float& xnew, float& wv)
{
    // mean = x/2 + 25*x/(x^2+1) + 8*cos(1.2*t); xnew = mean + noise*sqrt(10)
    const float mean = x * 0.5f + 25.0f * (x / (x * x + 1.0f)) + c;
    xnew = mean + n * 3.16227770f;                 // np.float32(sqrt(10))
    const float om = (xnew * xnew) / 20.0f;
    const float d  = ob - om;
    const float lp = -0.5f * d * d + (-0.9189385f); // -0.5*log(2*pi)
    wv = wt * __expf(lp);
}

// Pass 1: single read of all inputs (the ~2.5 TB/s-capped stream), writes
// np (nt; never re-read) and UNNORMALIZED w (cached; pass 2 re-reads it
// microseconds later -> L3/L2 candidate). Round-3 measured this byte mix
// at 82.5 us (writes ride along ~free next to the capped read stream).
__global__ __launch_bounds__(TPB) void pf_main(
    const float* __restrict__ particles,
    const float* __restrict__ weights,
    const float* __restrict__ obs,        // [B]
    const float* __restrict__ noise,
    const int*   __restrict__ tstep,      // [1]
    float* __restrict__ np_out,           // [B*N]
    float* __restrict__ w_out,            // [B*N] unnormalized after this pass
    float* __restrict__ partials)         // [B * BLOCKS_PER_BATCH]
{
    const int b     = blockIdx.x / BLOCKS_PER_BATCH;
    const int chunk = blockIdx.x % BLOCKS_PER_BATCH;
    const long base = (long)b * PF_N + (long)chunk * EPB
                    + (long)threadIdx.x * 4;

    const float ob = obs[b];
    const float c  = 8.0f * cosf(1.2f * (float)(*tstep));

    v4f x4[VPT], n4[VPT], wt4[VPT];
    #pragma unroll
    for (int k = 0; k < VPT; ++k)
        x4[k]  = *(const v4f*)(particles + base + (long)k * (TPB * 4));
    #pragma unroll
    for (int k = 0; k < VPT; ++k)
        n4[k]  = *(const v4f*)(noise + base + (long)k * (TPB * 4));
    #pragma unroll
    for (int k = 0; k < VPT; ++k)
        wt4[k] = *(const v4f*)(weights + base + (long)k * (TPB * 4));

    float lsum = 0.0f;
    #pragma unroll
    for (int k = 0; k < VPT; ++k) {
        v4f xn, wn;
        #pragma unroll
        for (int j = 0; j < 4; ++j) {
            float xnew, wv;
            compute_elem(x4[k][j], n4[k][j], wt4[k][j], c, ob, xnew, wv);
            xn[j] = xnew;
            wn[j] = wv;
            lsum += wv;
        }
        // np is never re-read: bypass cache.
        __builtin_nontemporal_store(xn, (v4f*)(np_out + base + (long)k * (TPB * 4)));
        // w IS re-read by pass 2: cached store so L3/L2 can serve it.
        *(v4f*)(w_out + base + (long)k * (TPB * 4)) = wn;
    }

    // 64-lane wave reduction, cross-wave via LDS, one store per block
    #pragma unroll
    for (int off = 32; off > 0; off >>= 1)
        lsum += __shfl_down(lsum, off, 64);

    __shared__ float red[TPB / 64];
    if ((threadIdx.x & 63) == 0) red[threadIdx.x >> 6] = lsum;
    __syncthreads();
    if (threadIdx.x == 0) {
        float s = 0.0f;
        #pragma unroll
        for (int i = 0; i < TPB / 64; ++i) s += red[i];
        partials[blockIdx.x] = s;   // no memset, no atomics needed
    }
}

// Pass 2: w *= 1/sum. Pure scale-copy (the pattern that hits ~6.3 TB/s on
// this chip), 67 MB read (L3-warm from pass 1) + 67 MB nt write.
__global__ __launch_bounds__(TPB) void pf_norm(
    float* __restrict__ w_out,
    const float* __restrict__ partials)   // [B * BLOCKS_PER_BATCH]
{
    const int b     = blockIdx.x / NORM_BPB;
    const int chunk = blockIdx.x % NORM_BPB;
    const long base = (long)b * PF_N + (long)chunk * NORM_EPB
                    + (long)threadIdx.x * 4;

    // 32 partials per batch; lanes 0-31 and 32-63 each hold the set
    // (lane&31); butterfly over offsets <32 sums within each half.
    const int lane = threadIdx.x & 63;
    float p = partials[b * BLOCKS_PER_BATCH + (lane & (BLOCKS_PER_BATCH - 1))];
    #pragma unroll
    for (int off = BLOCKS_PER_BATCH / 2; off > 0; off >>= 1)
        p += __shfl_xor(p, off, 64);
    const float inv = 1.0f / p;

    #pragma unroll
    for (int k = 0; k < NORM_VPT; ++k) {
        const long idx = base + (long)k * (TPB * 4);
        v4f v = *(const v4f*)(w_out + idx);
        v *= inv;
        // final w never re-read: bypass cache on the way out.
        __builtin_nontemporal_store(v, (v4f*)(w_out + idx));
    }
}

extern "C" void kernel_launch(void* const* d_in, const int* in_sizes, int n_in,
                              void* d_out, int out_size, void* d_ws, size_t ws_size,
                              hipStream_t stream) {
    const float* particles = (const float*)d_in[0];
    const float* weights   = (const float*)d_in[1];
    const float* obs       = (const float*)d_in[2];
    const float* noise     = (const float*)d_in[3];
    // d_in[4] = uniforms: dead code in the reference (resample output unused)
    const int*   tstep     = (const int*)d_in[5];

    float* np_out   = (float*)d_out;                     // new_particles [B*N]
    float* w_out    = (float*)d_out + (long)PF_B * PF_N; // weights      [B*N]
    float* partials = (float*)d_ws;                      // [B*32]

    pf_main<<<PF_B * BLOCKS_PER_BATCH, TPB, 0, stream>>>(
        particles, weights, obs, noise, tstep, np_out, w_out, partials);
    pf_norm<<<PF_B * NORM_BPB, TPB, 0, stream>>>(w_out, partials);
}

// Round 14
// 305.999 us; speedup vs baseline: 1.0870x; 1.0830x over previous
//
#include <hip/hip_runtime.h>
#include <math.h>

// Problem constants (from reference): B=128, N=131072, D=1
#define PF_B 128
#define PF_N 131072
#define TPB 256                 // threads per block
#define EPT 8                   // elements per thread (2 x float4) -- round-3 geometry
#define EPB (TPB * EPT)         // 2048 elements per block
#define BLOCKS_PER_BATCH (PF_N / EPB)   // 64 (== wave width, used by pf_norm)

// Pass 2 geometry: pure scale-copy of w
#define NORM_BPB 16                          // blocks per batch
#define NORM_EPB (PF_N / NORM_BPB)           // 8192 elems per block
#define NORM_VPT (NORM_EPB / (TPB * 4))      // 8 float4 per thread

typedef float v4f __attribute__((ext_vector_type(4)));

// d_out layout: [new_particles: B*N floats][w: B*N floats]
// d_ws  layout: [partials: B * BLOCKS_PER_BATCH floats = 8192 floats = 32 KB]

// Pass 1: EXACT round-3 measured-82.5us pattern: NT input loads (do not
// allocate 201 MB of single-use lines in L2/L3 -- cached loads here cost
// +23 us by fighting the store streams, round-13 evidence), interleaved
// load->compute->store, np via nt-store, w via cached store (pass 2 re-reads
// it microseconds later). Only delta vs round 3: partials store instead of
// memset+atomicAdd.
__global__ __launch_bounds__(TPB) void pf_main(
    const float* __restrict__ particles,
    const float* __restrict__ weights,
    const float* __restrict__ obs,        // [B]
    const float* __restrict__ noise,
    const int*   __restrict__ tstep,      // [1]
    float* __restrict__ np_out,           // [B*N]
    float* __restrict__ w_out,            // [B*N] unnormalized after this pass
    float* __restrict__ partials)         // [B * BLOCKS_PER_BATCH]
{
    const int b     = blockIdx.x / BLOCKS_PER_BATCH;
    const int chunk = blockIdx.x % BLOCKS_PER_BATCH;
    const long base = (long)b * PF_N + (long)chunk * EPB;

    const float ob     = obs[b];
    const float c      = 8.0f * cosf(1.2f * (float)(*tstep));
    const float sq10   = 3.16227770f;     // np.float32(sqrt(10))
    const float nhl2pi = -0.9189385f;     // -0.5*log(2*pi) in fp32

    float lsum = 0.0f;

    #pragma unroll
    for (int k = 0; k < EPT / 4; ++k) {
        const long idx = base + (long)k * (TPB * 4) + (long)threadIdx.x * 4;
        const v4f x4  = __builtin_nontemporal_load((const v4f*)(particles + idx));
        const v4f n4  = __builtin_nontemporal_load((const v4f*)(noise + idx));
        const v4f wt4 = __builtin_nontemporal_load((const v4f*)(weights + idx));

        v4f xn, wn;

        #pragma unroll
        for (int j = 0; j < 4; ++j) {
            const float x = x4[j];
            // mean = x/2 + 25*x/(x^2+1) + 8*cos(1.2*t)
            const float mean = x * 0.5f + 25.0f * (x / (x * x + 1.0f)) + c;
            const float xnew = mean + n4[j] * sq10;
            xn[j] = xnew;
            const float om = (xnew * xnew) / 20.0f;
            const float d  = ob - om;
            const float lp = -0.5f * d * d + nhl2pi;
            const float wv = wt4[j] * __expf(lp);
            wn[j] = wv;
            lsum += wv;
        }

        // np is never re-read: bypass cache.
        __builtin_nontemporal_store(xn, (v4f*)(np_out + idx));
        // w IS re-read by pass 2: cached store so L2/L3 can serve it.
        *(v4f*)(w_out + idx) = wn;
    }

    // wave (64-lane) reduction, then cross-wave via LDS, one store per block
    #pragma unroll
    for (int off = 32; off > 0; off >>= 1)
        lsum += __shfl_down(lsum, off, 64);

    __shared__ float red[TPB / 64];
    if ((threadIdx.x & 63) == 0) red[threadIdx.x >> 6] = lsum;
    __syncthreads();
    if (threadIdx.x == 0) {
        float s = 0.0f;
        #pragma unroll
        for (int i = 0; i < TPB / 64; ++i) s += red[i];
        partials[blockIdx.x] = s;   // no memset, no atomics needed
    }
}

// Pass 2: w *= 1/sum. Pure scale-copy: 67 MB read (L2/L3-warm from pass 1)
// + 67 MB nt write.
__global__ __launch_bounds__(TPB) void pf_norm(
    float* __restrict__ w_out,
    const float* __restrict__ partials)   // [B * BLOCKS_PER_BATCH]
{
    const int b     = blockIdx.x / NORM_BPB;
    const int chunk = blockIdx.x % NORM_BPB;
    const long base = (long)b * PF_N + (long)chunk * NORM_EPB
                    + (long)threadIdx.x * 4;

    // 64 partials per batch == one per lane; butterfly so all lanes get total.
    const int lane = threadIdx.x & 63;
    float p = partials[b * BLOCKS_PER_BATCH + lane];
    #pragma unroll
    for (int off = 32; off > 0; off >>= 1)
        p += __shfl_xor(p, off, 64);
    const float inv = 1.0f / p;

    #pragma unroll
    for (int k = 0; k < NORM_VPT; ++k) {
        const long idx = base + (long)k * (TPB * 4);
        v4f v = *(const v4f*)(w_out + idx);
        v *= inv;
        // final w never re-read: bypass cache on the way out.
        __builtin_nontemporal_store(v, (v4f*)(w_out + idx));
    }
}

extern "C" void kernel_launch(void* const* d_in, const int* in_sizes, int n_in,
                              void* d_out, int out_size, void* d_ws, size_t ws_size,
                              hipStream_t stream) {
    const float* particles = (const float*)d_in[0];
    const float* weights   = (const float*)d_in[1];
    const float* obs       = (const float*)d_in[2];
    const float* noise     = (const float*)d_in[3];
    // d_in[4] = uniforms: dead code in the reference (resample output unused)
    const int*   tstep     = (const int*)d_in[5];

    float* np_out   = (float*)d_out;                     // new_particles [B*N]
    float* w_out    = (float*)d_out + (long)PF_B * PF_N; // weights      [B*N]
    float* partials = (float*)d_ws;                      // [B*64] = 32 KB

    pf_main<<<PF_B * BLOCKS_PER_BATCH, TPB, 0, stream>>>(
        particles, weights, obs, noise, tstep, np_out, w_out, partials);
    pf_norm<<<PF_B * NORM_BPB, TPB, 0, stream>>>(w_out, partials);
}